// Round 6
// baseline (622.794 us; speedup 1.0000x reference)
//
#include <hip/hip_runtime.h>

constexpr int K_CODES = 512;
constexpr int D_DIM   = 64;
constexpr int HW      = 4096;               // 64*64
constexpr int BATCH   = 32;
constexpr int N_ROWS  = BATCH * HW;         // 131072
constexpr int HALF    = BATCH * D_DIM * HW; // elements per output tensor
constexpr int RPB     = 64;                 // rows per block (one per lane)
constexpr int KPW     = 128;                // codes per wave (512 / 4 waves)
constexpr int G       = 16;                 // codes in flight per thread
constexpr int C       = 8;                  // z dims per chunk

// ee[k] = |e_k|^2: sequential d, separate mul/add rounding (matches f32 reference)
__global__ void ee_precompute(const float* __restrict__ emb, float* __restrict__ ee) {
#pragma clang fp contract(off)
    int k = blockIdx.x * blockDim.x + threadIdx.x;
    if (k < K_CODES) {
        const float* w = emb + k * D_DIM;
        float acc = 0.f;
        for (int d = 0; d < D_DIM; ++d) { float q = w[d] * w[d]; acc = acc + q; }
        ee[k] = acc;
    }
}

// 256 threads = 4 waves over 64 rows; lane <-> row, wave <-> 128-code range.
// Codebook + ee via wave-uniform s_load (readfirstlane; proven round 4).
// z is streamed in 8-dim chunks from global (block slab = 16 KB -> L1-hot);
// live set = dot[16] + z8[8] + addr ~ 45 VGPR, so (256,8) gives 8 waves/EU
// with no remat pressure (round 4/5 failure modes addressed).
// Bit-exact f32 reference emulation (absmax 0.0, rounds 2-5):
//   dist = fl( fl(zz - fl(2*dot)) + ee ); zz sequential separate-rounded;
//   dot strictly d-ascending fma chain per code (chunking preserves order);
//   argmin first-occurrence (strict <, ascending k).
__global__ __launch_bounds__(256, 8) void vq_nearest(const float* __restrict__ zin,
                                                     const float* __restrict__ emb,
                                                     const float* __restrict__ ee,
                                                     float* __restrict__ out) {
#pragma clang fp contract(off)
    __shared__ float s_best[4][RPB];
    __shared__ int   s_bidx[4][RPB];

    const int tid  = threadIdx.x;
    const int wave = tid >> 6;
    const int lane = tid & 63;

    const int row = blockIdx.x * RPB + lane;
    const int b   = row >> 12;
    const int p   = row & (HW - 1);
    const float* zp = zin + (size_t)b * (D_DIM * HW) + p;

    // zz: strict sequential sum of squares, separate rounding
    float zz = 0.f;
#pragma unroll
    for (int d = 0; d < D_DIM; ++d) {
        const float zv = zp[(size_t)d * HW];
        const float q  = zv * zv;
        zz = zz + q;
    }

    // wave-uniform code range, forced into an SGPR
    const int kbase = __builtin_amdgcn_readfirstlane(wave) * KPW;
    const float* wbase  = emb + (size_t)kbase * D_DIM;  // uniform -> s_load
    const float* eebase = ee + kbase;                   // uniform -> s_load

    float best = 3.4e38f;
    int   bi   = kbase;

    for (int k0 = 0; k0 < KPW; k0 += G) {
        const float* w = wbase + (size_t)k0 * D_DIM;
        float dot[G];
#pragma unroll
        for (int j = 0; j < G; ++j) dot[j] = 0.f;

        // d ascending in chunks of C: per code the fma chain order is exactly
        // d = 0..63 (bit-identical to the validated unchunked version)
#pragma unroll
        for (int d0 = 0; d0 < D_DIM; d0 += C) {
            float z8[C];
#pragma unroll
            for (int dd = 0; dd < C; ++dd)
                z8[dd] = zp[(size_t)(d0 + dd) * HW];   // L1-hot after 1st group
#pragma unroll
            for (int dd = 0; dd < C; ++dd) {
                const float z = z8[dd];
#pragma unroll
                for (int j = 0; j < G; ++j)
                    dot[j] = __builtin_fmaf(w[j * D_DIM + d0 + dd], z, dot[j]);
            }
        }
#pragma unroll
        for (int j = 0; j < G; ++j) {
            const float m    = 2.0f * dot[j];        // exact
            const float s    = zz - m;               // one rounding
            const float dist = s + eebase[k0 + j];   // one rounding
            if (dist < best) { best = dist; bi = kbase + k0 + j; }
        }
    }

    s_best[wave][lane] = best;
    s_bidx[wave][lane] = bi;
    __syncthreads();

    // cross-wave argmin; wave order ascending in k, strict < keeps
    // first-occurrence semantics exact
    float b0 = s_best[0][lane];
    int   i0 = s_bidx[0][lane];
#pragma unroll
    for (int w2 = 1; w2 < 4; ++w2) {
        const float bw = s_best[w2][lane];
        if (bw < b0) { b0 = bw; i0 = s_bidx[w2][lane]; }
    }

    // gather + write both outputs; wave w covers d in [16w, 16w+16)
    const float* wb = emb + (size_t)i0 * D_DIM;
    float* o1 = out + (size_t)b * (D_DIM * HW) + p;
    float* o2 = o1 + HALF;
#pragma unroll
    for (int dd = 0; dd < 16; ++dd) {
        const int d = wave * 16 + dd;
        const float v = wb[d];
        o1[(size_t)d * HW] = v;
        o2[(size_t)d * HW] = v;
    }
}

extern "C" void kernel_launch(void* const* d_in, const int* in_sizes, int n_in,
                              void* d_out, int out_size, void* d_ws, size_t ws_size,
                              hipStream_t stream) {
    const float* z   = (const float*)d_in[0];
    const float* emb = (const float*)d_in[1];
    float* ee  = (float*)d_ws;
    float* out = (float*)d_out;
    hipLaunchKernelGGL(ee_precompute, dim3(2), dim3(256), 0, stream, emb, ee);
    hipLaunchKernelGGL(vq_nearest, dim3(N_ROWS / RPB), dim3(256), 0, stream,
                       z, emb, ee, out);
}

// Round 7
// 152.660 us; speedup vs baseline: 4.0796x; 4.0796x over previous
//
#include <hip/hip_runtime.h>

constexpr int K_CODES = 512;
constexpr int D_DIM   = 64;
constexpr int HW      = 4096;               // 64*64
constexpr int BATCH   = 32;
constexpr int N_ROWS  = BATCH * HW;         // 131072
constexpr int HALF    = BATCH * D_DIM * HW; // elements per output tensor
constexpr float MARGIN = 3e-4f;             // >> 3.4e-5 rigorous pairwise slack

typedef __attribute__((ext_vector_type(8))) short bf16x8;
typedef __attribute__((ext_vector_type(4))) float f32x4;

__device__ __forceinline__ unsigned short f32_bf16_rn(float x) {
    unsigned u = __builtin_bit_cast(unsigned, x);
    unsigned r = (u + 0x7FFFu + ((u >> 16) & 1u)) >> 16;   // round-to-nearest-even
    return (unsigned short)r;
}
__device__ __forceinline__ float bf16_f32(unsigned short h) {
    unsigned u = ((unsigned)h) << 16;
    return __builtin_bit_cast(float, u);
}

// ---- prep: ee[k]=|e_k|^2 (exact sequential f32, matches reference bit-for-bit),
//            e_hi/e_lo = two-term bf16 expansion of the codebook
__global__ void prep(const float* __restrict__ emb, float* __restrict__ ee,
                     unsigned short* __restrict__ ehi, unsigned short* __restrict__ elo) {
#pragma clang fp contract(off)
    int k = blockIdx.x * 256 + threadIdx.x;
    if (k >= K_CODES) return;
    const float* w = emb + k * D_DIM;
    float acc = 0.f;
    for (int d = 0; d < D_DIM; ++d) {
        float v = w[d];
        float q = v * v; acc = acc + q;
        unsigned short h = f32_bf16_rn(v);
        float r = v - bf16_f32(h);
        ehi[k * D_DIM + d] = h;
        elo[k * D_DIM + d] = f32_bf16_rn(r);
    }
    ee[k] = acc;
}

// ---- main: 256 thr = 4 waves; wave owns 32 rows (2 rowgroups of 16) x all 512 codes.
// Pass A: MFMA approx dists -> per-row min. Pass B: re-MFMA, collect codes within
// MARGIN of min. Pass C: exact re-rank of candidates with the validated bit-exact
// recipe. Pass D: coalesced gather-write of both outputs.
__global__ __launch_bounds__(256, 4) void vq_mfma(const float* __restrict__ zin,
                                                  const float* __restrict__ emb,
                                                  const float* __restrict__ ee,
                                                  const unsigned short* __restrict__ ehi,
                                                  const unsigned short* __restrict__ elo,
                                                  float* __restrict__ out) {
#pragma clang fp contract(off)
    __shared__ float s_ee[K_CODES];
    __shared__ int   s_cnt[128];
    __shared__ int   s_cand[128][8];
    __shared__ int   s_win[128];

    const int tid  = threadIdx.x;
    const int wid  = tid >> 6;
    const int lane = tid & 63;
    const int l15  = lane & 15;
    const int lq   = lane >> 4;          // 0..3

    s_ee[tid]       = ee[tid];
    s_ee[tid + 256] = ee[tid + 256];
    if (tid < 128) s_cnt[tid] = 0;
    __syncthreads();

    // ---- z B-fragments: B[k][n] = z[row n][dim k]; lane supplies k=seg*32+lq*8+j, n=l15
    const float* zp[2];
#pragma unroll
    for (int rg = 0; rg < 2; ++rg) {
        const int n = blockIdx.x * 128 + wid * 32 + rg * 16 + l15;
        zp[rg] = zin + (size_t)(n >> 12) * (D_DIM * HW) + (n & (HW - 1));
    }
    bf16x8 zh[2][2], zl[2][2];
#pragma unroll
    for (int rg = 0; rg < 2; ++rg)
#pragma unroll
        for (int s = 0; s < 2; ++s) {
            float rz[8];
#pragma unroll
            for (int j = 0; j < 8; ++j)
                rz[j] = zp[rg][(size_t)(s * 32 + lq * 8 + j) * HW];
#pragma unroll
            for (int j = 0; j < 8; ++j) {
                unsigned short h = f32_bf16_rn(rz[j]);
                zh[rg][s][j] = (short)h;
                zl[rg][s][j] = (short)f32_bf16_rn(rz[j] - bf16_f32(h));
            }
        }

    // ---- pass A: per-lane running min of approx dists
    float minv[2] = {3.4e38f, 3.4e38f};
    for (int ct = 0; ct < 32; ++ct) {
        const int crow = ct * 16 + l15;                         // A row = code
        const bf16x8 ah0 = *(const bf16x8*)(ehi + crow * 64 +      lq * 8);
        const bf16x8 ah1 = *(const bf16x8*)(ehi + crow * 64 + 32 + lq * 8);
        const bf16x8 al0 = *(const bf16x8*)(elo + crow * 64 +      lq * 8);
        const bf16x8 al1 = *(const bf16x8*)(elo + crow * 64 + 32 + lq * 8);
#pragma unroll
        for (int rg = 0; rg < 2; ++rg) {
            f32x4 acc = {0.f, 0.f, 0.f, 0.f};
            acc = __builtin_amdgcn_mfma_f32_16x16x32_bf16(ah0, zh[rg][0], acc, 0, 0, 0);
            acc = __builtin_amdgcn_mfma_f32_16x16x32_bf16(ah1, zh[rg][1], acc, 0, 0, 0);
            acc = __builtin_amdgcn_mfma_f32_16x16x32_bf16(al0, zh[rg][0], acc, 0, 0, 0);
            acc = __builtin_amdgcn_mfma_f32_16x16x32_bf16(al1, zh[rg][1], acc, 0, 0, 0);
            acc = __builtin_amdgcn_mfma_f32_16x16x32_bf16(ah0, zl[rg][0], acc, 0, 0, 0);
            acc = __builtin_amdgcn_mfma_f32_16x16x32_bf16(ah1, zl[rg][1], acc, 0, 0, 0);
#pragma unroll
            for (int r = 0; r < 4; ++r) {
                const int c = ct * 16 + lq * 4 + r;             // D row = code
                const float dist = s_ee[c] - 2.f * acc[r];
                minv[rg] = fminf(minv[rg], dist);
            }
        }
    }
    float thr[2];
#pragma unroll
    for (int rg = 0; rg < 2; ++rg) {
        float v = minv[rg];
        v = fminf(v, __shfl_xor(v, 16, 64));
        v = fminf(v, __shfl_xor(v, 32, 64));
        thr[rg] = v + MARGIN;
    }

    // ---- pass B: identical MFMA, collect candidates within margin
    for (int ct = 0; ct < 32; ++ct) {
        const int crow = ct * 16 + l15;
        const bf16x8 ah0 = *(const bf16x8*)(ehi + crow * 64 +      lq * 8);
        const bf16x8 ah1 = *(const bf16x8*)(ehi + crow * 64 + 32 + lq * 8);
        const bf16x8 al0 = *(const bf16x8*)(elo + crow * 64 +      lq * 8);
        const bf16x8 al1 = *(const bf16x8*)(elo + crow * 64 + 32 + lq * 8);
#pragma unroll
        for (int rg = 0; rg < 2; ++rg) {
            f32x4 acc = {0.f, 0.f, 0.f, 0.f};
            acc = __builtin_amdgcn_mfma_f32_16x16x32_bf16(ah0, zh[rg][0], acc, 0, 0, 0);
            acc = __builtin_amdgcn_mfma_f32_16x16x32_bf16(ah1, zh[rg][1], acc, 0, 0, 0);
            acc = __builtin_amdgcn_mfma_f32_16x16x32_bf16(al0, zh[rg][0], acc, 0, 0, 0);
            acc = __builtin_amdgcn_mfma_f32_16x16x32_bf16(al1, zh[rg][1], acc, 0, 0, 0);
            acc = __builtin_amdgcn_mfma_f32_16x16x32_bf16(ah0, zl[rg][0], acc, 0, 0, 0);
            acc = __builtin_amdgcn_mfma_f32_16x16x32_bf16(ah1, zl[rg][1], acc, 0, 0, 0);
#pragma unroll
            for (int r = 0; r < 4; ++r) {
                const int c = ct * 16 + lq * 4 + r;
                const float dist = s_ee[c] - 2.f * acc[r];
                if (dist <= thr[rg]) {
                    const int rowl = wid * 32 + rg * 16 + l15;
                    const int slot = atomicAdd(&s_cnt[rowl], 1);
                    if (slot < 8) s_cand[rowl][slot] = c;
                }
            }
        }
    }
    __syncthreads();

    // ---- pass C: exact re-rank (bit-exact reference recipe, rounds 2-6)
    if (lane < 32) {
        const int rowl = wid * 32 + lane;
        const int n    = blockIdx.x * 128 + rowl;
        const float* zq = zin + (size_t)(n >> 12) * (D_DIM * HW) + (n & (HW - 1));
        const int cnt = s_cnt[rowl];
        int win;
        if (cnt == 1) {
            win = s_cand[rowl][0];
        } else {
            float zz = 0.f;
            for (int d = 0; d < D_DIM; ++d) {
                const float v = zq[(size_t)d * HW];
                const float q = v * v; zz = zz + q;
            }
            float best = 3.4e38f; win = 0;
            if (cnt <= 8) {
                // sort candidate list ascending (atomic append order is arbitrary)
                for (int i = 0; i < cnt - 1; ++i)
                    for (int j2 = 0; j2 < cnt - 1 - i; ++j2)
                        if (s_cand[rowl][j2] > s_cand[rowl][j2 + 1]) {
                            int t = s_cand[rowl][j2];
                            s_cand[rowl][j2] = s_cand[rowl][j2 + 1];
                            s_cand[rowl][j2 + 1] = t;
                        }
                for (int i = 0; i < cnt; ++i) {
                    const int k = s_cand[rowl][i];
                    const float* w = emb + (size_t)k * D_DIM;
                    float dot = 0.f;
                    for (int d = 0; d < D_DIM; ++d)
                        dot = __builtin_fmaf(w[d], zq[(size_t)d * HW], dot);
                    const float m = 2.0f * dot;
                    const float s = zz - m;
                    const float dist = s + s_ee[k];
                    if (dist < best) { best = dist; win = k; }
                }
            } else {
                // overflow fallback (practically unreachable): full exact scan
                for (int k = 0; k < K_CODES; ++k) {
                    const float* w = emb + (size_t)k * D_DIM;
                    float dot = 0.f;
                    for (int d = 0; d < D_DIM; ++d)
                        dot = __builtin_fmaf(w[d], zq[(size_t)d * HW], dot);
                    const float m = 2.0f * dot;
                    const float s = zz - m;
                    const float dist = s + s_ee[k];
                    if (dist < best) { best = dist; win = k; }
                }
            }
        }
        s_win[rowl] = win;
    }
    __syncthreads();

    // ---- pass D: gather + coalesced write of both outputs
    const int drow = tid & 127;
    const int dh   = tid >> 7;                       // d-half 0/1
    const int n2   = blockIdx.x * 128 + drow;
    float* o1 = out + (size_t)(n2 >> 12) * (D_DIM * HW) + (n2 & (HW - 1));
    float* o2 = o1 + HALF;
    const float* wv = emb + (size_t)s_win[drow] * D_DIM;
#pragma unroll
    for (int dd = 0; dd < 32; ++dd) {
        const int d = dh * 32 + dd;
        const float v = wv[d];
        o1[(size_t)d * HW] = v;
        o2[(size_t)d * HW] = v;
    }
}

// ---- fallback (validated round-2 kernel, used only if ws is too small)
__global__ __launch_bounds__(256) void vq_fallback(const float* __restrict__ zin,
                                                   const float* __restrict__ emb,
                                                   float* __restrict__ out) {
#pragma clang fp contract(off)
    __shared__ float s_ee[K_CODES];
    const int tid = threadIdx.x;
    for (int k = tid; k < K_CODES; k += 256) {
        const float* w = emb + k * D_DIM;
        float acc = 0.f;
        for (int d = 0; d < D_DIM; ++d) { float q = w[d] * w[d]; acc = acc + q; }
        s_ee[k] = acc;
    }
    __syncthreads();
    const int n = blockIdx.x * 256 + tid;
    const int b = n >> 12;
    const int p = n & (HW - 1);
    const float* zp = zin + (size_t)b * (D_DIM * HW) + p;
    float zr[D_DIM];
#pragma unroll
    for (int d = 0; d < D_DIM; ++d) zr[d] = zp[(size_t)d * HW];
    float zz = 0.f;
#pragma unroll
    for (int d = 0; d < D_DIM; ++d) { float q = zr[d] * zr[d]; zz = zz + q; }
    float best = 3.4e38f; int bi = 0;
    for (int k0 = 0; k0 < K_CODES; k0 += 8) {
        const float* w = emb + (size_t)k0 * D_DIM;
        float dot[8];
#pragma unroll
        for (int j = 0; j < 8; ++j) dot[j] = 0.f;
#pragma unroll
        for (int d = 0; d < D_DIM; ++d) {
            const float z = zr[d];
#pragma unroll
            for (int j = 0; j < 8; ++j)
                dot[j] = __builtin_fmaf(w[j * D_DIM + d], z, dot[j]);
        }
#pragma unroll
        for (int j = 0; j < 8; ++j) {
            const float m = 2.0f * dot[j];
            const float s = zz - m;
            const float dist = s + s_ee[k0 + j];
            if (dist < best) { best = dist; bi = k0 + j; }
        }
    }
    const float* wb = emb + (size_t)bi * D_DIM;
    float* o1 = out + (size_t)b * (D_DIM * HW) + p;
    float* o2 = o1 + HALF;
#pragma unroll
    for (int d = 0; d < D_DIM; ++d) {
        const float v = wb[d];
        o1[(size_t)d * HW] = v;
        o2[(size_t)d * HW] = v;
    }
}

extern "C" void kernel_launch(void* const* d_in, const int* in_sizes, int n_in,
                              void* d_out, int out_size, void* d_ws, size_t ws_size,
                              hipStream_t stream) {
    const float* z   = (const float*)d_in[0];
    const float* emb = (const float*)d_in[1];
    float* out = (float*)d_out;

    const size_t need = 2048 + 2 * (size_t)K_CODES * D_DIM * sizeof(unsigned short);
    if (ws_size >= need) {
        float* ee = (float*)d_ws;
        unsigned short* ehi = (unsigned short*)((char*)d_ws + 2048);
        unsigned short* elo = (unsigned short*)((char*)d_ws + 2048 + K_CODES * D_DIM * 2);
        hipLaunchKernelGGL(prep, dim3(2), dim3(256), 0, stream, emb, ee, ehi, elo);
        hipLaunchKernelGGL(vq_mfma, dim3(N_ROWS / 128), dim3(256), 0, stream,
                           z, emb, ee, ehi, elo, out);
    } else {
        hipLaunchKernelGGL(vq_fallback, dim3(N_ROWS / 256), dim3(256), 0, stream,
                           z, emb, out);
    }
}